// Round 6
// baseline (479.277 us; speedup 1.0000x reference)
//
#include <hip/hip_runtime.h>
#include <cstdint>

// ---------- types ----------
typedef __attribute__((ext_vector_type(8))) __bf16 bf16x8;   // MFMA A/B operand (4 VGPRs)
typedef __attribute__((ext_vector_type(4))) float  f32x4;    // MFMA C/D operand
typedef __attribute__((ext_vector_type(8))) unsigned short ushort8;

#define DIM 4096
#define SEQ 2048
#define NH  32
#define NKV 8
#define HD  128

__device__ __forceinline__ float b2f(unsigned short u) {
  union { unsigned int i; float f; } v; v.i = ((unsigned int)u) << 16; return v.f;
}
__device__ __forceinline__ unsigned short f2b(float f) {
  union { float f; unsigned int i; } v; v.f = f;
  unsigned int r = v.i + 0x7fffu + ((v.i >> 16) & 1u);   // RNE
  return (unsigned short)(r >> 16);
}

// async global->LDS, 16B per lane. LDS dest = wave-uniform base + lane*16.
__device__ __forceinline__ void gl_lds16(const void* g, void* l) {
  __builtin_amdgcn_global_load_lds(
      (const __attribute__((address_space(1))) void*)(uintptr_t)g,
      (__attribute__((address_space(3))) void*)(uintptr_t)l,
      16, 0, 0);
}

// ---------------------------------------------------------------------------
// fp32 -> bf16 conversion (8 elems/thread).
// ---------------------------------------------------------------------------
__global__ __launch_bounds__(256) void f32_to_bf16(const float* __restrict__ src,
                                                   unsigned short* __restrict__ dst, int n) {
  const int i = (blockIdx.x * 256 + threadIdx.x) * 8;
  if (i >= n) return;
  const float4 a = *(const float4*)(src + i);
  const float4 b = *(const float4*)(src + i + 4);
  ushort8 o;
  o[0] = f2b(a.x); o[1] = f2b(a.y); o[2] = f2b(a.z); o[3] = f2b(a.w);
  o[4] = f2b(b.x); o[5] = f2b(b.y); o[6] = f2b(b.z); o[7] = f2b(b.w);
  *(ushort8*)(dst + i) = o;
}

// ---------------------------------------------------------------------------
// GEMM (m97 structure, kept for split-path kv GEMM only).
// ---------------------------------------------------------------------------
template <bool OUT_F32>
__global__ __launch_bounds__(256) void gemm_bt(const unsigned short* __restrict__ A,
                                               const unsigned short* __restrict__ B,
                                               void* __restrict__ Cv,
                                               int M, int N, int K) {
  __shared__ __align__(16) unsigned short As[128 * 32];  // [m][k] rows of 64B
  __shared__ __align__(16) unsigned short Bs[128 * 32];  // [n][k]
  const int n0   = blockIdx.x * 128;
  const int m0   = blockIdx.y * 128;
  const int tid  = threadIdx.x;
  const int w    = tid >> 6;
  const int lane = tid & 63;
  const int quad = lane >> 4;
  const int l15  = lane & 15;
  const int wm   = (w & 1) * 64;
  const int wn   = (w >> 1) * 64;

  const f32x4 fzero = {0.f, 0.f, 0.f, 0.f};
  f32x4 acc[4][4];
#pragma unroll
  for (int i = 0; i < 4; ++i)
#pragma unroll
    for (int j = 0; j < 4; ++j) acc[i][j] = fzero;

  const int srow = lane >> 2;        // chunk = 16 rows of 64B
  const int scol = (lane & 3) * 8;

  for (int k0 = 0; k0 < K; k0 += 32) {
    __syncthreads();
#pragma unroll
    for (int cc = 0; cc < 2; ++cc) {
      const int c   = w * 2 + cc;
      const int row = c * 16 + srow;
      gl_lds16(A + (size_t)(m0 + row) * K + k0 + scol, (char*)As + c * 1024);
      gl_lds16(B + (size_t)(n0 + row) * K + k0 + scol, (char*)Bs + c * 1024);
    }
    __syncthreads();

    bf16x8 af[4], bfr[4];
#pragma unroll
    for (int i = 0; i < 4; ++i) {
      af[i]  = *(const bf16x8*)(As + (wm + i * 16 + l15) * 32 + quad * 8);
      bfr[i] = *(const bf16x8*)(Bs + (wn + i * 16 + l15) * 32 + quad * 8);
    }
#pragma unroll
    for (int i = 0; i < 4; ++i)
#pragma unroll
      for (int j = 0; j < 4; ++j)
        acc[i][j] = __builtin_amdgcn_mfma_f32_16x16x32_bf16(af[i], bfr[j], acc[i][j], 0, 0, 0);
  }

#pragma unroll
  for (int i = 0; i < 4; ++i)
#pragma unroll
    for (int j = 0; j < 4; ++j) {
      const int m = m0 + wm + i * 16 + quad * 4;
      const int n = n0 + wn + j * 16 + l15;
      if (OUT_F32) {
        float* cp = (float*)Cv + (size_t)m * N + n;
#pragma unroll
        for (int r = 0; r < 4; ++r) cp[(size_t)r * N] = acc[i][j][r];
      } else {
        unsigned short* cp = (unsigned short*)Cv + (size_t)m * N + n;
#pragma unroll
        for (int r = 0; r < 4; ++r) cp[(size_t)r * N] = f2b(acc[i][j][r]);
      }
    }
}

// ---------------------------------------------------------------------------
// GEMM 256(M)x192(N), BK=64, 8 waves (2M x 4N), grid 32x8 = 256 blocks.
// m201-style per-phase interleave (T3): 4 phases per K-tile, ks-major
// {ks0 x m0-3, ks0 x m4-7, ks1 x m0-3, ks1 x m4-7}. Each phase:
//   reads -> s_barrier -> lgkmcnt(0) -> setprio(1) 12 MFMA setprio(0) -> s_barrier
// Mechanism (why round-5's flat stream serialized, sum-model 3760 cyc/tile):
// reads issued BEFORE a barrier drain during the barrier wait; waves reach
// the post-MFMA barrier right after ISSUE (results not yet needed), so the
// next phase's reads overlap the MFMA pipe tail. Counters r5: ds(2112) +
// mfma(1862) ~= measured -> zero overlap without this structure.
// Staging t+1 -> buf^1 right after entry barrier (legal: every wave executed
// lgkmcnt(0) on its buf^1 reads before arriving). vmcnt(0) at entry waits
// loads issued a full K-tile earlier (~0 stall). Per-element MFMA order
// (ks0 then ks1, tiles ascending) identical to prior rounds -> bit-identical C.
// ---------------------------------------------------------------------------
template <bool OUT_F32>
__global__ __launch_bounds__(512, 2) void gemm256x192(const unsigned short* __restrict__ A,
                                                      const unsigned short* __restrict__ B,
                                                      void* __restrict__ Cv,
                                                      int M, int N, int K) {
  __shared__ __align__(16) unsigned short As[2][256 * 64];
  __shared__ __align__(16) unsigned short Bs[2][192 * 64];

  const int n0   = blockIdx.x * 192;
  const int m0   = blockIdx.y * 256;
  const int tid  = threadIdx.x;
  const int w    = tid >> 6;          // 0..7
  const int lane = tid & 63;
  const int quad = lane >> 4;
  const int l15  = lane & 15;
  const int wm   = (w >> 2) * 128;    // 2 waves in M, 128 rows each
  const int wn   = (w & 3) * 48;      // 4 waves in N, 48 cols each

  // staging: chunk = 8 rows x 64 cols (1 KiB); pre-swizzled global source
  // so LDS slot g at row r holds global granule g ^ (r&7)
  const int srow = lane >> 3;
  const int sgr  = (lane & 7) ^ srow;
  const unsigned short* aS = A + (size_t)(m0 + srow) * K + sgr * 8;
  const unsigned short* bS = B + (size_t)(n0 + srow) * K + sgr * 8;

  // ds_read byte offsets: global granule (ks*4+quad) lives at slot (g ^ (l15&7))
  const int gr0 = ((quad)     ^ (l15 & 7)) * 8;
  const int gr1 = ((quad + 4) ^ (l15 & 7)) * 8;

  const f32x4 fzero = {0.f, 0.f, 0.f, 0.f};
  f32x4 acc[8][3];
#pragma unroll
  for (int i = 0; i < 8; ++i)
#pragma unroll
    for (int j = 0; j < 3; ++j) acc[i][j] = fzero;

  const int NT = K >> 6;

  // prologue: stage tile 0 into buf 0 (7 loads: 4 A-chunks + 3 B-chunks)
#pragma unroll
  for (int i = 0; i < 4; ++i) {
    const int c = w * 4 + i;
    gl_lds16(aS + (size_t)c * 8 * K, (char*)As[0] + c * 1024);
  }
#pragma unroll
  for (int i = 0; i < 3; ++i) {
    const int c = w * 3 + i;
    gl_lds16(bS + (size_t)c * 8 * K, (char*)Bs[0] + c * 1024);
  }

  for (int t = 0; t < NT; ++t) {
    const unsigned short* Ab = As[t & 1] + (wm + l15) * 64;
    const unsigned short* Bb = Bs[t & 1] + (wn + l15) * 64;

    // entry: my tile-t gloads landed; my tile-(t-1) ds_reads long drained
    asm volatile("s_waitcnt vmcnt(0) lgkmcnt(0)" ::: "memory");
    __builtin_amdgcn_s_barrier();     // collectively: tile t visible, buf^1 free
    __builtin_amdgcn_sched_barrier(0);

    // stage tile t+1 into the other buffer (vmcnt pipe; not counted by lgkmcnt)
    if (t + 1 < NT) {
      const int koff = (t + 1) * 64;
      unsigned short* Ad = As[(t + 1) & 1];
      unsigned short* Bd = Bs[(t + 1) & 1];
#pragma unroll
      for (int i = 0; i < 4; ++i) {
        const int c = w * 4 + i;
        gl_lds16(aS + (size_t)c * 8 * K + koff, (char*)Ad + c * 1024);
      }
#pragma unroll
      for (int i = 0; i < 3; ++i) {
        const int c = w * 3 + i;
        gl_lds16(bS + (size_t)c * 8 * K + koff, (char*)Bd + c * 1024);
      }
    }

    // ---- P0: ks0 x m0..3 (reads: 3 B ks0 + 4 A) ----
    bf16x8 b0[3];
#pragma unroll
    for (int nf = 0; nf < 3; ++nf) b0[nf] = *(const bf16x8*)(Bb + nf * 1024 + gr0);
    bf16x8 a0[4];
#pragma unroll
    for (int mf = 0; mf < 4; ++mf) a0[mf] = *(const bf16x8*)(Ab + mf * 1024 + gr0);
    __builtin_amdgcn_s_barrier();
    asm volatile("s_waitcnt lgkmcnt(0)" ::: "memory");
    __builtin_amdgcn_sched_barrier(0);
    __builtin_amdgcn_s_setprio(1);
#pragma unroll
    for (int mf = 0; mf < 4; ++mf)
#pragma unroll
      for (int nf = 0; nf < 3; ++nf)
        acc[mf][nf] = __builtin_amdgcn_mfma_f32_16x16x32_bf16(a0[mf], b0[nf], acc[mf][nf], 0, 0, 0);
    __builtin_amdgcn_s_setprio(0);
    __builtin_amdgcn_s_barrier();
    __builtin_amdgcn_sched_barrier(0);

    // ---- P1: ks0 x m4..7 (reads: 4 A) ----
    bf16x8 a1[4];
#pragma unroll
    for (int mf = 0; mf < 4; ++mf) a1[mf] = *(const bf16x8*)(Ab + (4 + mf) * 1024 + gr0);
    __builtin_amdgcn_s_barrier();
    asm volatile("s_waitcnt lgkmcnt(0)" ::: "memory");
    __builtin_amdgcn_sched_barrier(0);
    __builtin_amdgcn_s_setprio(1);
#pragma unroll
    for (int mf = 0; mf < 4; ++mf)
#pragma unroll
      for (int nf = 0; nf < 3; ++nf)
        acc[4 + mf][nf] = __builtin_amdgcn_mfma_f32_16x16x32_bf16(a1[mf], b0[nf], acc[4 + mf][nf], 0, 0, 0);
    __builtin_amdgcn_s_setprio(0);
    __builtin_amdgcn_s_barrier();
    __builtin_amdgcn_sched_barrier(0);

    // ---- P2: ks1 x m0..3 (reads: 3 B ks1 + 4 A) ----
    bf16x8 b1[3];
#pragma unroll
    for (int nf = 0; nf < 3; ++nf) b1[nf] = *(const bf16x8*)(Bb + nf * 1024 + gr1);
    bf16x8 a2[4];
#pragma unroll
    for (int mf = 0; mf < 4; ++mf) a2[mf] = *(const bf16x8*)(Ab + mf * 1024 + gr1);
    __builtin_amdgcn_s_barrier();
    asm volatile("s_waitcnt lgkmcnt(0)" ::: "memory");
    __builtin_amdgcn_sched_barrier(0);
    __builtin_amdgcn_s_setprio(1);
#pragma unroll
    for (int mf = 0; mf < 4; ++mf)
#pragma unroll
      for (int nf = 0; nf < 3; ++nf)
        acc[mf][nf] = __builtin_amdgcn_mfma_f32_16x16x32_bf16(a2[mf], b1[nf], acc[mf][nf], 0, 0, 0);
    __builtin_amdgcn_s_setprio(0);
    __builtin_amdgcn_s_barrier();
    __builtin_amdgcn_sched_barrier(0);

    // ---- P3: ks1 x m4..7 (reads: 4 A); trailing barrier merged w/ next entry ----
    bf16x8 a3[4];
#pragma unroll
    for (int mf = 0; mf < 4; ++mf) a3[mf] = *(const bf16x8*)(Ab + (4 + mf) * 1024 + gr1);
    __builtin_amdgcn_s_barrier();
    asm volatile("s_waitcnt lgkmcnt(0)" ::: "memory");
    __builtin_amdgcn_sched_barrier(0);
    __builtin_amdgcn_s_setprio(1);
#pragma unroll
    for (int mf = 0; mf < 4; ++mf)
#pragma unroll
      for (int nf = 0; nf < 3; ++nf)
        acc[4 + mf][nf] = __builtin_amdgcn_mfma_f32_16x16x32_bf16(a3[mf], b1[nf], acc[4 + mf][nf], 0, 0, 0);
    __builtin_amdgcn_s_setprio(0);
  }

#pragma unroll
  for (int mf = 0; mf < 8; ++mf)
#pragma unroll
    for (int nf = 0; nf < 3; ++nf) {
      const int m = m0 + wm + mf * 16 + quad * 4;
      const int n = n0 + wn + nf * 16 + l15;
      if (OUT_F32) {
        float* cp = (float*)Cv + (size_t)m * N + n;
#pragma unroll
        for (int r = 0; r < 4; ++r) cp[(size_t)r * N] = acc[mf][nf][r];
      } else {
        unsigned short* cp = (unsigned short*)Cv + (size_t)m * N + n;
#pragma unroll
        for (int r = 0; r < 4; ++r) cp[(size_t)r * N] = f2b(acc[mf][nf][r]);
      }
    }
}

// ---------------------------------------------------------------------------
// GEMM 128(M)x256(N), BK=64, 8 waves (2M x 4N), grid 16x16 = 256 blocks.
// Same m201-style 4-phase interleave as gemm256x192:
// {ks0 x m01, ks0 x m23, ks1 x m01, ks1 x m23}, 8 MFMA/phase.
// ---------------------------------------------------------------------------
template <bool OUT_F32>
__global__ __launch_bounds__(512, 2) void gemm128n256(const unsigned short* __restrict__ A,
                                                      const unsigned short* __restrict__ B,
                                                      void* __restrict__ Cv,
                                                      int M, int N, int K) {
  __shared__ __align__(16) unsigned short As[2][128 * 64];
  __shared__ __align__(16) unsigned short Bs[2][256 * 64];

  const int n0   = blockIdx.x * 256;
  const int m0   = blockIdx.y * 128;
  const int tid  = threadIdx.x;
  const int w    = tid >> 6;          // 0..7
  const int lane = tid & 63;
  const int quad = lane >> 4;
  const int l15  = lane & 15;
  const int wm   = (w >> 2) * 64;     // 2 waves in M, 64 rows each
  const int wn   = (w & 3) * 64;      // 4 waves in N, 64 cols each

  const int srow = lane >> 3;
  const int sgr  = (lane & 7) ^ srow;
  const unsigned short* aS = A + (size_t)(m0 + srow) * K + sgr * 8;
  const unsigned short* bS = B + (size_t)(n0 + srow) * K + sgr * 8;

  const int gr0 = ((quad)     ^ (l15 & 7)) * 8;
  const int gr1 = ((quad + 4) ^ (l15 & 7)) * 8;

  const f32x4 fzero = {0.f, 0.f, 0.f, 0.f};
  f32x4 acc[4][4];
#pragma unroll
  for (int i = 0; i < 4; ++i)
#pragma unroll
    for (int j = 0; j < 4; ++j) acc[i][j] = fzero;

  const int NT = K >> 6;

  // prologue: stage tile 0 into buf 0 (6 loads: 2 A-chunks + 4 B-chunks)
#pragma unroll
  for (int i = 0; i < 2; ++i) {
    const int c = w * 2 + i;
    gl_lds16(aS + (size_t)c * 8 * K, (char*)As[0] + c * 1024);
  }
#pragma unroll
  for (int i = 0; i < 4; ++i) {
    const int c = w * 4 + i;
    gl_lds16(bS + (size_t)c * 8 * K, (char*)Bs[0] + c * 1024);
  }

  for (int t = 0; t < NT; ++t) {
    const unsigned short* Ab = As[t & 1] + (wm + l15) * 64;
    const unsigned short* Bb = Bs[t & 1] + (wn + l15) * 64;

    asm volatile("s_waitcnt vmcnt(0) lgkmcnt(0)" ::: "memory");
    __builtin_amdgcn_s_barrier();
    __builtin_amdgcn_sched_barrier(0);

    if (t + 1 < NT) {
      const int koff = (t + 1) * 64;
      unsigned short* Ad = As[(t + 1) & 1];
      unsigned short* Bd = Bs[(t + 1) & 1];
#pragma unroll
      for (int i = 0; i < 2; ++i) {
        const int c = w * 2 + i;
        gl_lds16(aS + (size_t)c * 8 * K + koff, (char*)Ad + c * 1024);
      }
#pragma unroll
      for (int i = 0; i < 4; ++i) {
        const int c = w * 4 + i;
        gl_lds16(bS + (size_t)c * 8 * K + koff, (char*)Bd + c * 1024);
      }
    }

    // ---- P0: ks0 x m01 (reads: 4 B ks0 + 2 A) ----
    bf16x8 b0[4];
#pragma unroll
    for (int nf = 0; nf < 4; ++nf) b0[nf] = *(const bf16x8*)(Bb + nf * 1024 + gr0);
    bf16x8 a0[2];
#pragma unroll
    for (int mf = 0; mf < 2; ++mf) a0[mf] = *(const bf16x8*)(Ab + mf * 1024 + gr0);
    __builtin_amdgcn_s_barrier();
    asm volatile("s_waitcnt lgkmcnt(0)" ::: "memory");
    __builtin_amdgcn_sched_barrier(0);
    __builtin_amdgcn_s_setprio(1);
#pragma unroll
    for (int mf = 0; mf < 2; ++mf)
#pragma unroll
      for (int nf = 0; nf < 4; ++nf)
        acc[mf][nf] = __builtin_amdgcn_mfma_f32_16x16x32_bf16(a0[mf], b0[nf], acc[mf][nf], 0, 0, 0);
    __builtin_amdgcn_s_setprio(0);
    __builtin_amdgcn_s_barrier();
    __builtin_amdgcn_sched_barrier(0);

    // ---- P1: ks0 x m23 ----
    bf16x8 a1[2];
#pragma unroll
    for (int mf = 0; mf < 2; ++mf) a1[mf] = *(const bf16x8*)(Ab + (2 + mf) * 1024 + gr0);
    __builtin_amdgcn_s_barrier();
    asm volatile("s_waitcnt lgkmcnt(0)" ::: "memory");
    __builtin_amdgcn_sched_barrier(0);
    __builtin_amdgcn_s_setprio(1);
#pragma unroll
    for (int mf = 0; mf < 2; ++mf)
#pragma unroll
      for (int nf = 0; nf < 4; ++nf)
        acc[2 + mf][nf] = __builtin_amdgcn_mfma_f32_16x16x32_bf16(a1[mf], b0[nf], acc[2 + mf][nf], 0, 0, 0);
    __builtin_amdgcn_s_setprio(0);
    __builtin_amdgcn_s_barrier();
    __builtin_amdgcn_sched_barrier(0);

    // ---- P2: ks1 x m01 (reads: 4 B ks1 + 2 A) ----
    bf16x8 b1[4];
#pragma unroll
    for (int nf = 0; nf < 4; ++nf) b1[nf] = *(const bf16x8*)(Bb + nf * 1024 + gr1);
    bf16x8 a2[2];
#pragma unroll
    for (int mf = 0; mf < 2; ++mf) a2[mf] = *(const bf16x8*)(Ab + mf * 1024 + gr1);
    __builtin_amdgcn_s_barrier();
    asm volatile("s_waitcnt lgkmcnt(0)" ::: "memory");
    __builtin_amdgcn_sched_barrier(0);
    __builtin_amdgcn_s_setprio(1);
#pragma unroll
    for (int mf = 0; mf < 2; ++mf)
#pragma unroll
      for (int nf = 0; nf < 4; ++nf)
        acc[mf][nf] = __builtin_amdgcn_mfma_f32_16x16x32_bf16(a2[mf], b1[nf], acc[mf][nf], 0, 0, 0);
    __builtin_amdgcn_s_setprio(0);
    __builtin_amdgcn_s_barrier();
    __builtin_amdgcn_sched_barrier(0);

    // ---- P3: ks1 x m23; trailing barrier merged w/ next entry ----
    bf16x8 a3[2];
#pragma unroll
    for (int mf = 0; mf < 2; ++mf) a3[mf] = *(const bf16x8*)(Ab + (2 + mf) * 1024 + gr1);
    __builtin_amdgcn_s_barrier();
    asm volatile("s_waitcnt lgkmcnt(0)" ::: "memory");
    __builtin_amdgcn_sched_barrier(0);
    __builtin_amdgcn_s_setprio(1);
#pragma unroll
    for (int mf = 0; mf < 2; ++mf)
#pragma unroll
      for (int nf = 0; nf < 4; ++nf)
        acc[2 + mf][nf] = __builtin_amdgcn_mfma_f32_16x16x32_bf16(a3[mf], b1[nf], acc[2 + mf][nf], 0, 0, 0);
    __builtin_amdgcn_s_setprio(0);
  }

#pragma unroll
  for (int mf = 0; mf < 4; ++mf)
#pragma unroll
    for (int nf = 0; nf < 4; ++nf) {
      const int m = m0 + wm + mf * 16 + quad * 4;
      const int n = n0 + wn + nf * 16 + l15;
      if (OUT_F32) {
        float* cp = (float*)Cv + (size_t)m * N + n;
#pragma unroll
        for (int r = 0; r < 4; ++r) cp[(size_t)r * N] = acc[mf][nf][r];
      } else {
        unsigned short* cp = (unsigned short*)Cv + (size_t)m * N + n;
#pragma unroll
        for (int r = 0; r < 4; ++r) cp[(size_t)r * N] = f2b(acc[mf][nf][r]);
      }
    }
}

// ---------------------------------------------------------------------------
// RoPE (interleaved pairs) in-place on bf16 q (S,32,128) and k (S,8,128).
// ---------------------------------------------------------------------------
__global__ void rope_kernel(unsigned short* __restrict__ q, int qstride,
                            unsigned short* __restrict__ k, int kstride,
                            const float* __restrict__ Ct, const float* __restrict__ St) {
  const int idx = blockIdx.x * 256 + threadIdx.x;
  const int total = SEQ * (NH * 64 + NKV * 64);
  if (idx >= total) return;
  const int s = idx / 2560;
  const int r = idx - s * 2560;
  unsigned short* base;
  int i;
  if (r < NH * 64) {
    const int h = r >> 6; i = r & 63;
    base = q + (size_t)s * qstride + h * HD + 2 * i;
  } else {
    const int r2 = r - NH * 64; const int h = r2 >> 6; i = r2 & 63;
    base = k + (size_t)s * kstride + h * HD + 2 * i;
  }
  const float c  = Ct[s * 64 + i];
  const float sn = St[s * 64 + i];
  const float xr = b2f(base[0]);
  const float xi = b2f(base[1]);
  base[0] = f2b(xr * c - xi * sn);
  base[1] = f2b(xr * sn + xi * c);
}

// ---------------------------------------------------------------------------
// V transpose (bf16): v[S][1024] (row stride vstride) -> vt[1024][S]
// ---------------------------------------------------------------------------
__global__ __launch_bounds__(256) void transpose_v(const unsigned short* __restrict__ v,
                                                   int vstride,
                                                   unsigned short* __restrict__ vt) {
  __shared__ unsigned short tile[64][72];
  const int bs = blockIdx.x;
  const int bd = blockIdx.y;
  const int t  = threadIdx.x;
  const int r  = t >> 2;
  const int c0 = (t & 3) * 16;
  const unsigned short* src = v + (size_t)(bs * 64 + r) * vstride + bd * 64 + c0;
#pragma unroll
  for (int i = 0; i < 2; ++i) {
    ushort8 d = *(const ushort8*)(src + i * 8);
#pragma unroll
    for (int e = 0; e < 8; ++e) tile[r][c0 + i * 8 + e] = d[e];
  }
  __syncthreads();
  unsigned short* dst = vt + (size_t)(bd * 64 + r) * SEQ + bs * 64 + c0;
#pragma unroll
  for (int i = 0; i < 2; ++i) {
    ushort8 o;
#pragma unroll
    for (int e = 0; e < 8; ++e) o[e] = tile[c0 + i * 8 + e][r];
    *(ushort8*)(dst + i * 8) = o;
  }
}

// ---------------------------------------------------------------------------
// Flash attention v3 (causal, GQA rep=4), bf16. (unchanged, verified)
// ---------------------------------------------------------------------------
__global__ __launch_bounds__(256) void attn_kernel(const unsigned short* __restrict__ Q, int qstride,
                                                   const unsigned short* __restrict__ K, int kstride,
                                                   const unsigned short* __restrict__ VT,
                                                   unsigned short* __restrict__ O) {
  const int bid  = blockIdx.x;
  const int h    = bid & 31;
  const int pr   = bid >> 5;          // 0..7
  const int g    = h >> 2;            // kv head
  const int tid  = threadIdx.x;
  const int w    = tid >> 6;
  const int lane = tid & 63;
  const int quad = lane >> 4;
  const int l15  = lane & 15;

  __shared__ __align__(16) unsigned short Ks[64 * 128];      // [key][d], swizzled
  __shared__ __align__(16) unsigned short Vs[128 * 64];      // [d][key], swizzled
  __shared__ __align__(16) unsigned short Ps[4][32 * 64];    // per-wave P, swizzled

  const float scale = 0.08838834764831845f;   // 1/sqrt(128)
  const f32x4 fzero = {0.f, 0.f, 0.f, 0.f};

  bf16x8 onesf;
#pragma unroll
  for (int e = 0; e < 8; ++e) onesf[e] = (__bf16)1.0f;

  const int ks_row = (lane >> 4);
  const int ks_q   = (lane & 15);
  const int vs_row = (lane >> 3);
  const int vs_q   = (lane & 7) ^ (lane >> 3);

  unsigned short* pw = Ps[w];

  for (int phase = 0; phase < 2; ++phase) {
    const int qt    = phase ? (15 - pr) : pr;
    const int qrow0 = qt * 128 + w * 32;

    bf16x8 qf[2][4];
#pragma unroll
    for (int gq = 0; gq < 2; ++gq) {
      const unsigned short* qb = Q + (size_t)(qrow0 + gq * 16 + l15) * qstride + h * HD + quad * 8;
#pragma unroll
      for (int c = 0; c < 4; ++c) qf[gq][c] = *(const bf16x8*)(qb + c * 32);
    }

    f32x4 oa[2][8];
    f32x4 ls[2];
#pragma unroll
    for (int gq = 0; gq < 2; ++gq) {
      ls[gq] = fzero;
#pragma unroll
      for (int i = 0; i < 8; ++i) oa[gq][i] = fzero;
    }

    const int n_tiles = 2 * qt + 2;           // 64-key tiles, causal bound

    for (int kt = 0; kt < n_tiles; ++kt) {
      const int kv0 = kt * 64;
      __syncthreads();                        // WAR: prior ds_reads drained
#pragma unroll
      for (int cc = 0; cc < 4; ++cc) {
        const int c = w * 4 + cc;
        {  // K tile: 64 rows x 256B; chunk = 4 rows
          const int row = c * 4 + ks_row;
          const int qch = ks_q ^ (row & 15);
          gl_lds16(K + (size_t)(kv0 + row) * kstride + g * HD + qch * 8, (char*)Ks + c * 1024);
        }
        {  // V^T tile: 128 rows x 128B; chunk = 8 rows
          const int row = c * 8 + vs_row;
          gl_lds16(VT + (size_t)(g * HD + row) * SEQ + kv0 + vs_q * 8, (char*)Vs + c * 1024);
        }
      }
      __syncthreads();                        // staged K/V^T visible

      // ---- S = Q K^T ----
      f32x4 s[2][4];
#pragma unroll
      for (int gq = 0; gq < 2; ++gq)
#pragma unroll
        for (int ks = 0; ks < 4; ++ks) s[gq][ks] = fzero;
#pragma unroll
      for (int c = 0; c < 4; ++c)
#pragma unroll
        for (int ks = 0; ks < 4; ++ks) {
          const int row = ks * 16 + l15;
          const int p   = (c * 4 + quad) ^ l15;
          bf16x8 kf = *(const bf16x8*)(Ks + row * 128 + p * 8);
          s[0][ks] = __builtin_amdgcn_mfma_f32_16x16x32_bf16(qf[0][c], kf, s[0][ks], 0, 0, 0);
          s[1][ks] = __builtin_amdgcn_mfma_f32_16x16x32_bf16(qf[1][c], kf, s[1][ks], 0, 0, 0);
        }

      // ---- static softmax: e = exp(s*scale), masked; write P (swizzled) ----
#pragma unroll
      for (int gq = 0; gq < 2; ++gq)
#pragma unroll
        for (int r = 0; r < 4; ++r) {
          const int qrow = qrow0 + gq * 16 + quad * 4 + r;
          const int prow = gq * 16 + quad * 4 + r;
#pragma unroll
          for (int ks = 0; ks < 4; ++ks) {
            const float ex = __expf(s[gq][ks][r] * scale);
            const float e  = (kv0 + ks * 16 + l15 <= qrow) ? ex : 0.f;
            const int qc = ks * 2 + (l15 >> 3);
            const int p  = qc ^ (prow & 7);
            pw[prow * 64 + p * 8 + (l15 & 7)] = f2b(e);
          }
        }
      // no barrier: Ps[w] is per-wave (lgkmcnt orders ds_write->ds_read)

      // ---- O += P V ; ls += P * ones ----
#pragma unroll
      for (int ki = 0; ki < 2; ++ki) {
        bf16x8 pf[2];
#pragma unroll
        for (int gq = 0; gq < 2; ++gq) {
          const int row = gq * 16 + l15;
          const int p   = (ki * 4 + quad) ^ (l15 & 7);
          pf[gq] = *(const bf16x8*)(pw + row * 64 + p * 8);
        }
        ls[0] = __builtin_amdgcn_mfma_f32_16x16x32_bf16(pf[0], onesf, ls[0], 0, 0, 0);
        ls[1] = __builtin_amdgcn_mfma_f32_16x16x32_bf16(pf[1], onesf, ls[1], 0, 0, 0);
#pragma unroll
        for (int nt = 0; nt < 8; ++nt) {
          const int vrow = nt * 16 + l15;
          const int p    = (ki * 4 + quad) ^ (l15 & 7);
          bf16x8 vf = *(const bf16x8*)(Vs + vrow * 64 + p * 8);
          oa[0][nt] = __builtin_amdgcn_mfma_f32_16x16x32_bf16(pf[0], vf, oa[0][nt], 0, 0, 0);
          oa[1][nt] = __builtin_amdgcn_mfma_f32_16x16x32_bf16(pf[1], vf, oa[1][nt], 0, 0, 0);
        }
      }
    }

    // epilogue: divide by rowsum (ls col-replicated), store bf16
#pragma unroll
    for (int gq = 0; gq < 2; ++gq)
#pragma unroll
      for (int r = 0; r < 4; ++r) {
        const float inv = 1.f / ls[gq][r];
        const int qrow = qrow0 + gq * 16 + quad * 4 + r;
        unsigned short* orow = O + (size_t)qrow * DIM + h * HD;
#pragma unroll
        for (int nt = 0; nt < 8; ++nt) orow[nt * 16 + l15] = f2b(oa[gq][nt][r] * inv);
      }
  }
}

// ---------------------------------------------------------------------------
extern "C" void kernel_launch(void* const* d_in, const int* in_sizes, int n_in,
                              void* d_out, int out_size, void* d_ws, size_t ws_size,
                              hipStream_t stream) {
  const float* x  = (const float*)d_in[0];
  const float* wq = (const float*)d_in[1];
  const float* wk = (const float*)d_in[2];
  const float* wv = (const float*)d_in[3];
  const float* wo = (const float*)d_in[4];
  const float* fc = (const float*)d_in[5];
  const float* fs = (const float*)d_in[6];
  float* outp = (float*)d_out;

  const dim3 blk(256);
  const size_t M1 = 1024 * 1024;
  const int nx  = SEQ * DIM;        // 8M
  const int nqw = DIM * DIM;        // 16M
  const int nkw = NKV * HD * DIM;   // 4M
  const int total = SEQ * (NH * 64 + NKV * 64);

  const size_t fused_elems = (8 + 24 + 12 + 2 + 8) * M1;   // 54M elems = 108MB

  if (ws_size >= fused_elems * 2) {
    // ---- fused QKV path ----
    unsigned short* xb   = (unsigned short*)d_ws;
    unsigned short* wbuf = xb   + 8  * M1;   // 24M elems: wq|wk|wv (reused for wo)
    unsigned short* qkv  = wbuf + 24 * M1;   // 12M elems: 2048 x 6144
    unsigned short* vtb  = qkv  + 12 * M1;   // 2M
    unsigned short* aob  = vtb  + 2  * M1;   // 8M

    f32_to_bf16<<<dim3(nx  / 2048), blk, 0, stream>>>(x,  xb, nx);
    f32_to_bf16<<<dim3(nqw / 2048), blk, 0, stream>>>(wq, wbuf, nqw);
    f32_to_bf16<<<dim3(nkw / 2048), blk, 0, stream>>>(wk, wbuf + 16 * M1, nkw);
    f32_to_bf16<<<dim3(nkw / 2048), blk, 0, stream>>>(wv, wbuf + 20 * M1, nkw);

    gemm256x192<false><<<dim3(6144 / 192, SEQ / 256), dim3(512), 0, stream>>>(xb, wbuf, qkv,
                                                                              SEQ, 6144, DIM);

    rope_kernel<<<dim3((total + 255) / 256), blk, 0, stream>>>(qkv, 6144, qkv + 4096, 6144, fc, fs);
    transpose_v<<<dim3(SEQ / 64, 1024 / 64), blk, 0, stream>>>(qkv + 5120, 6144, vtb);
    attn_kernel<<<dim3(256), blk, 0, stream>>>(qkv, 6144, qkv + 4096, 6144, vtb, aob);

    f32_to_bf16<<<dim3(nqw / 2048), blk, 0, stream>>>(wo, wbuf, nqw);
    gemm128n256<true><<<dim3(DIM / 256, SEQ / 128), dim3(512), 0, stream>>>(aob, wbuf, outp,
                                                                            SEQ, DIM, DIM);
  } else {
    // ---- split path (92MB, known-good): q GEMM + fused kv GEMM ----
    unsigned short* xb   = (unsigned short*)d_ws;
    unsigned short* wbuf = xb   + 8  * M1;   // 16M elems
    unsigned short* qb   = wbuf + 16 * M1;   // 8M
    unsigned short* kvb  = qb   + 8  * M1;   // 4M: 2048 x 2048 (k|v)
    unsigned short* vtb  = kvb  + 4  * M1;   // 2M
    unsigned short* aob  = vtb  + 2  * M1;   // 8M

    f32_to_bf16<<<dim3(nx  / 2048), blk, 0, stream>>>(x,  xb, nx);
    f32_to_bf16<<<dim3(nqw / 2048), blk, 0, stream>>>(wq, wbuf, nqw);
    gemm128n256<false><<<dim3(DIM / 256, SEQ / 128), dim3(512), 0, stream>>>(xb, wbuf, qb,
                                                                             SEQ, DIM, DIM);

    f32_to_bf16<<<dim3(nkw / 2048), blk, 0, stream>>>(wk, wbuf, nkw);
    f32_to_bf16<<<dim3(nkw / 2048), blk, 0, stream>>>(wv, wbuf + 4 * M1, nkw);
    gemm_bt<false><<<dim3(2048 / 128, SEQ / 128), blk, 0, stream>>>(xb, wbuf, kvb, SEQ, 2048, DIM);

    rope_kernel<<<dim3((total + 255) / 256), blk, 0, stream>>>(qb, 4096, kvb, 2048, fc, fs);
    transpose_v<<<dim3(SEQ / 64, 1024 / 64), blk, 0, stream>>>(kvb + 1024, 2048, vtb);
    attn_kernel<<<dim3(256), blk, 0, stream>>>(qb, 4096, kvb, 2048, vtb, aob);

    f32_to_bf16<<<dim3(nqw / 2048), blk, 0, stream>>>(wo, wbuf, nqw);
    gemm128n256<true><<<dim3(DIM / 256, SEQ / 128), dim3(512), 0, stream>>>(aob, wbuf, outp,
                                                                            SEQ, DIM, DIM);
  }
}

// Round 7
// 467.572 us; speedup vs baseline: 1.0250x; 1.0250x over previous
//
#include <hip/hip_runtime.h>
#include <cstdint>

// ---------- types ----------
typedef __attribute__((ext_vector_type(8))) __bf16 bf16x8;   // MFMA A/B operand (4 VGPRs)
typedef __attribute__((ext_vector_type(4))) float  f32x4;    // MFMA C/D operand
typedef __attribute__((ext_vector_type(8))) unsigned short ushort8;

#define DIM 4096
#define SEQ 2048
#define NH  32
#define NKV 8
#define HD  128

__device__ __forceinline__ float b2f(unsigned short u) {
  union { unsigned int i; float f; } v; v.i = ((unsigned int)u) << 16; return v.f;
}
__device__ __forceinline__ unsigned short f2b(float f) {
  union { float f; unsigned int i; } v; v.f = f;
  unsigned int r = v.i + 0x7fffu + ((v.i >> 16) & 1u);   // RNE
  return (unsigned short)(r >> 16);
}

// async global->LDS, 16B per lane. LDS dest = wave-uniform base + lane*16.
__device__ __forceinline__ void gl_lds16(const void* g, void* l) {
  __builtin_amdgcn_global_load_lds(
      (const __attribute__((address_space(1))) void*)(uintptr_t)g,
      (__attribute__((address_space(3))) void*)(uintptr_t)l,
      16, 0, 0);
}

// ---------------------------------------------------------------------------
// fp32 -> bf16 conversion (8 elems/thread).
// ---------------------------------------------------------------------------
__global__ __launch_bounds__(256) void f32_to_bf16(const float* __restrict__ src,
                                                   unsigned short* __restrict__ dst, int n) {
  const int i = (blockIdx.x * 256 + threadIdx.x) * 8;
  if (i >= n) return;
  const float4 a = *(const float4*)(src + i);
  const float4 b = *(const float4*)(src + i + 4);
  ushort8 o;
  o[0] = f2b(a.x); o[1] = f2b(a.y); o[2] = f2b(a.z); o[3] = f2b(a.w);
  o[4] = f2b(b.x); o[5] = f2b(b.y); o[6] = f2b(b.z); o[7] = f2b(b.w);
  *(ushort8*)(dst + i) = o;
}

// ---------------------------------------------------------------------------
// GEMM (m97 structure, kept for split-path kv GEMM only).
// ---------------------------------------------------------------------------
template <bool OUT_F32>
__global__ __launch_bounds__(256) void gemm_bt(const unsigned short* __restrict__ A,
                                               const unsigned short* __restrict__ B,
                                               void* __restrict__ Cv,
                                               int M, int N, int K) {
  __shared__ __align__(16) unsigned short As[128 * 32];  // [m][k] rows of 64B
  __shared__ __align__(16) unsigned short Bs[128 * 32];  // [n][k]
  const int n0   = blockIdx.x * 128;
  const int m0   = blockIdx.y * 128;
  const int tid  = threadIdx.x;
  const int w    = tid >> 6;
  const int lane = tid & 63;
  const int quad = lane >> 4;
  const int l15  = lane & 15;
  const int wm   = (w & 1) * 64;
  const int wn   = (w >> 1) * 64;

  const f32x4 fzero = {0.f, 0.f, 0.f, 0.f};
  f32x4 acc[4][4];
#pragma unroll
  for (int i = 0; i < 4; ++i)
#pragma unroll
    for (int j = 0; j < 4; ++j) acc[i][j] = fzero;

  const int srow = lane >> 2;        // chunk = 16 rows of 64B
  const int scol = (lane & 3) * 8;

  for (int k0 = 0; k0 < K; k0 += 32) {
    __syncthreads();
#pragma unroll
    for (int cc = 0; cc < 2; ++cc) {
      const int c   = w * 2 + cc;
      const int row = c * 16 + srow;
      gl_lds16(A + (size_t)(m0 + row) * K + k0 + scol, (char*)As + c * 1024);
      gl_lds16(B + (size_t)(n0 + row) * K + k0 + scol, (char*)Bs + c * 1024);
    }
    __syncthreads();

    bf16x8 af[4], bfr[4];
#pragma unroll
    for (int i = 0; i < 4; ++i) {
      af[i]  = *(const bf16x8*)(As + (wm + i * 16 + l15) * 32 + quad * 8);
      bfr[i] = *(const bf16x8*)(Bs + (wn + i * 16 + l15) * 32 + quad * 8);
    }
#pragma unroll
    for (int i = 0; i < 4; ++i)
#pragma unroll
      for (int j = 0; j < 4; ++j)
        acc[i][j] = __builtin_amdgcn_mfma_f32_16x16x32_bf16(af[i], bfr[j], acc[i][j], 0, 0, 0);
  }

#pragma unroll
  for (int i = 0; i < 4; ++i)
#pragma unroll
    for (int j = 0; j < 4; ++j) {
      const int m = m0 + wm + i * 16 + quad * 4;
      const int n = n0 + wn + j * 16 + l15;
      if (OUT_F32) {
        float* cp = (float*)Cv + (size_t)m * N + n;
#pragma unroll
        for (int r = 0; r < 4; ++r) cp[(size_t)r * N] = acc[i][j][r];
      } else {
        unsigned short* cp = (unsigned short*)Cv + (size_t)m * N + n;
#pragma unroll
        for (int r = 0; r < 4; ++r) cp[(size_t)r * N] = f2b(acc[i][j][r]);
      }
    }
}

// ---------------------------------------------------------------------------
// GEMM 128(M) x NF*64(N), BK=64, 8 waves (2M x 4N), grid 32x16 = 512 blocks
// = 2 blocks/CU. C = A[M,K]*B[N,K]^T, bf16.
//
// WHY 2 blocks/CU (round-6 lesson): at 1 block/CU all 8 waves are barrier-
// locked in the same phase -> LDS-read burst (matrix idle) then MFMA burst
// (LDS idle); measured tile time = ds+mfma SUM (3760 cyc) across three
// different barrier schedules (r4/r5/r6). Two co-resident blocks desync
// naturally (m114 co-schedule) -> one block's reads overlap the other's
// MFMAs. LDS: NF=3 -> 2x(128+192)x64x2B = 80 KiB = exactly 160/2.
// __launch_bounds__(512,4) forces <=128 VGPR (needed for 4 waves/SIMD).
// K-loop = round-5 flat one-barrier structure (best-known, verified):
// entry {vmcnt(0) lgkmcnt(0); barrier} -> stage t+1 into buf^1 -> reads+MFMA.
// Swizzle: pre-swizzled global source + XOR ds_read (verified 0 conflicts).
// Accumulation order per element (tiles ascending, ks0 then ks1) identical
// to all prior rounds -> bit-identical C.
// ---------------------------------------------------------------------------
template <int NF, bool OUT_F32>
__global__ __launch_bounds__(512, 4) void gemm128(const unsigned short* __restrict__ A,
                                                  const unsigned short* __restrict__ B,
                                                  void* __restrict__ Cv,
                                                  int M, int N, int K) {
  __shared__ __align__(16) unsigned short As[2][128 * 64];
  __shared__ __align__(16) unsigned short Bs[2][NF * 64 * 64];

  const int n0   = blockIdx.x * (NF * 64);
  const int m0   = blockIdx.y * 128;
  const int tid  = threadIdx.x;
  const int w    = tid >> 6;          // 0..7
  const int lane = tid & 63;
  const int quad = lane >> 4;
  const int l15  = lane & 15;
  const int wm   = (w >> 2) * 64;     // 2 waves in M, 64 rows each
  const int wn   = (w & 3) * (NF * 16);  // 4 waves in N, NF*16 cols each

  // staging: chunk = 8 rows x 64 cols (1 KiB); pre-swizzled global source
  // so LDS slot g at row r holds global granule g ^ (r&7)
  const int srow = lane >> 3;
  const int sgr  = (lane & 7) ^ srow;
  const unsigned short* aS = A + (size_t)(m0 + srow) * K + sgr * 8;
  const unsigned short* bS = B + (size_t)(n0 + srow) * K + sgr * 8;

  // ds_read byte offsets: global granule (ks*4+quad) lives at slot (g ^ (l15&7))
  const int gr0 = ((quad)     ^ (l15 & 7)) * 8;
  const int gr1 = ((quad + 4) ^ (l15 & 7)) * 8;

  const f32x4 fzero = {0.f, 0.f, 0.f, 0.f};
  f32x4 acc[4][NF];
#pragma unroll
  for (int i = 0; i < 4; ++i)
#pragma unroll
    for (int j = 0; j < NF; ++j) acc[i][j] = fzero;

  const int NT = K >> 6;

  // prologue: stage tile 0 into buf 0 (2 A-chunks + NF B-chunks per wave)
#pragma unroll
  for (int i = 0; i < 2; ++i) {
    const int c = w * 2 + i;            // A: 16 chunks over 8 waves
    gl_lds16(aS + (size_t)c * 8 * K, (char*)As[0] + c * 1024);
  }
#pragma unroll
  for (int i = 0; i < NF; ++i) {
    const int c = w * NF + i;           // B: NF*8 chunks over 8 waves
    gl_lds16(bS + (size_t)c * 8 * K, (char*)Bs[0] + c * 1024);
  }

  for (int t = 0; t < NT; ++t) {
    const unsigned short* Ab = As[t & 1] + (wm + l15) * 64;
    const unsigned short* Bb = Bs[t & 1] + (wn + l15) * 64;

    // my tile-t gloads landed AND my tile-(t-1) ds_reads drained
    asm volatile("s_waitcnt vmcnt(0) lgkmcnt(0)" ::: "memory");
    __builtin_amdgcn_s_barrier();     // collectively: tile t visible, buf^1 free
    __builtin_amdgcn_sched_barrier(0);

    // stage tile t+1 into the other buffer
    if (t + 1 < NT) {
      const int koff = (t + 1) * 64;
      unsigned short* Ad = As[(t + 1) & 1];
      unsigned short* Bd = Bs[(t + 1) & 1];
#pragma unroll
      for (int i = 0; i < 2; ++i) {
        const int c = w * 2 + i;
        gl_lds16(aS + (size_t)c * 8 * K + koff, (char*)Ad + c * 1024);
      }
#pragma unroll
      for (int i = 0; i < NF; ++i) {
        const int c = w * NF + i;
        gl_lds16(bS + (size_t)c * 8 * K + koff, (char*)Bd + c * 1024);
      }
    }

    // B fragments once, then 2 mf-pair groups; reads grouped per pair so the
    // compiler's counted lgkmcnt overlaps LDS drain with MFMA issue.
    bf16x8 bfr[NF][2];
#pragma unroll
    for (int nf = 0; nf < NF; ++nf) {
      bfr[nf][0] = *(const bf16x8*)(Bb + nf * 1024 + gr0);
      bfr[nf][1] = *(const bf16x8*)(Bb + nf * 1024 + gr1);
    }
#pragma unroll
    for (int mp = 0; mp < 2; ++mp) {
      bf16x8 a0[2], a1[2];
      a0[0] = *(const bf16x8*)(Ab + (mp * 2 + 0) * 1024 + gr0);
      a0[1] = *(const bf16x8*)(Ab + (mp * 2 + 0) * 1024 + gr1);
      a1[0] = *(const bf16x8*)(Ab + (mp * 2 + 1) * 1024 + gr0);
      a1[1] = *(const bf16x8*)(Ab + (mp * 2 + 1) * 1024 + gr1);
      __builtin_amdgcn_s_setprio(1);
#pragma unroll
      for (int ks = 0; ks < 2; ++ks)
#pragma unroll
        for (int nf = 0; nf < NF; ++nf) {
          acc[mp * 2 + 0][nf] = __builtin_amdgcn_mfma_f32_16x16x32_bf16(a0[ks], bfr[nf][ks],
                                                                        acc[mp * 2 + 0][nf], 0, 0, 0);
          acc[mp * 2 + 1][nf] = __builtin_amdgcn_mfma_f32_16x16x32_bf16(a1[ks], bfr[nf][ks],
                                                                        acc[mp * 2 + 1][nf], 0, 0, 0);
        }
      __builtin_amdgcn_s_setprio(0);
    }
  }

#pragma unroll
  for (int mf = 0; mf < 4; ++mf)
#pragma unroll
    for (int nf = 0; nf < NF; ++nf) {
      const int m = m0 + wm + mf * 16 + quad * 4;
      const int n = n0 + wn + nf * 16 + l15;
      if (OUT_F32) {
        float* cp = (float*)Cv + (size_t)m * N + n;
#pragma unroll
        for (int r = 0; r < 4; ++r) cp[(size_t)r * N] = acc[mf][nf][r];
      } else {
        unsigned short* cp = (unsigned short*)Cv + (size_t)m * N + n;
#pragma unroll
        for (int r = 0; r < 4; ++r) cp[(size_t)r * N] = f2b(acc[mf][nf][r]);
      }
    }
}

// ---------------------------------------------------------------------------
// RoPE (interleaved pairs) in-place on bf16 q (S,32,128) and k (S,8,128).
// ---------------------------------------------------------------------------
__global__ void rope_kernel(unsigned short* __restrict__ q, int qstride,
                            unsigned short* __restrict__ k, int kstride,
                            const float* __restrict__ Ct, const float* __restrict__ St) {
  const int idx = blockIdx.x * 256 + threadIdx.x;
  const int total = SEQ * (NH * 64 + NKV * 64);
  if (idx >= total) return;
  const int s = idx / 2560;
  const int r = idx - s * 2560;
  unsigned short* base;
  int i;
  if (r < NH * 64) {
    const int h = r >> 6; i = r & 63;
    base = q + (size_t)s * qstride + h * HD + 2 * i;
  } else {
    const int r2 = r - NH * 64; const int h = r2 >> 6; i = r2 & 63;
    base = k + (size_t)s * kstride + h * HD + 2 * i;
  }
  const float c  = Ct[s * 64 + i];
  const float sn = St[s * 64 + i];
  const float xr = b2f(base[0]);
  const float xi = b2f(base[1]);
  base[0] = f2b(xr * c - xi * sn);
  base[1] = f2b(xr * sn + xi * c);
}

// ---------------------------------------------------------------------------
// V transpose (bf16): v[S][1024] (row stride vstride) -> vt[1024][S]
// ---------------------------------------------------------------------------
__global__ __launch_bounds__(256) void transpose_v(const unsigned short* __restrict__ v,
                                                   int vstride,
                                                   unsigned short* __restrict__ vt) {
  __shared__ unsigned short tile[64][72];
  const int bs = blockIdx.x;
  const int bd = blockIdx.y;
  const int t  = threadIdx.x;
  const int r  = t >> 2;
  const int c0 = (t & 3) * 16;
  const unsigned short* src = v + (size_t)(bs * 64 + r) * vstride + bd * 64 + c0;
#pragma unroll
  for (int i = 0; i < 2; ++i) {
    ushort8 d = *(const ushort8*)(src + i * 8);
#pragma unroll
    for (int e = 0; e < 8; ++e) tile[r][c0 + i * 8 + e] = d[e];
  }
  __syncthreads();
  unsigned short* dst = vt + (size_t)(bd * 64 + r) * SEQ + bs * 64 + c0;
#pragma unroll
  for (int i = 0; i < 2; ++i) {
    ushort8 o;
#pragma unroll
    for (int e = 0; e < 8; ++e) o[e] = tile[c0 + i * 8 + e][r];
    *(ushort8*)(dst + i * 8) = o;
  }
}

// ---------------------------------------------------------------------------
// Flash attention v3 (causal, GQA rep=4), bf16. (unchanged, verified)
// ---------------------------------------------------------------------------
__global__ __launch_bounds__(256) void attn_kernel(const unsigned short* __restrict__ Q, int qstride,
                                                   const unsigned short* __restrict__ K, int kstride,
                                                   const unsigned short* __restrict__ VT,
                                                   unsigned short* __restrict__ O) {
  const int bid  = blockIdx.x;
  const int h    = bid & 31;
  const int pr   = bid >> 5;          // 0..7
  const int g    = h >> 2;            // kv head
  const int tid  = threadIdx.x;
  const int w    = tid >> 6;
  const int lane = tid & 63;
  const int quad = lane >> 4;
  const int l15  = lane & 15;

  __shared__ __align__(16) unsigned short Ks[64 * 128];      // [key][d], swizzled
  __shared__ __align__(16) unsigned short Vs[128 * 64];      // [d][key], swizzled
  __shared__ __align__(16) unsigned short Ps[4][32 * 64];    // per-wave P, swizzled

  const float scale = 0.08838834764831845f;   // 1/sqrt(128)
  const f32x4 fzero = {0.f, 0.f, 0.f, 0.f};

  bf16x8 onesf;
#pragma unroll
  for (int e = 0; e < 8; ++e) onesf[e] = (__bf16)1.0f;

  const int ks_row = (lane >> 4);
  const int ks_q   = (lane & 15);
  const int vs_row = (lane >> 3);
  const int vs_q   = (lane & 7) ^ (lane >> 3);

  unsigned short* pw = Ps[w];

  for (int phase = 0; phase < 2; ++phase) {
    const int qt    = phase ? (15 - pr) : pr;
    const int qrow0 = qt * 128 + w * 32;

    bf16x8 qf[2][4];
#pragma unroll
    for (int gq = 0; gq < 2; ++gq) {
      const unsigned short* qb = Q + (size_t)(qrow0 + gq * 16 + l15) * qstride + h * HD + quad * 8;
#pragma unroll
      for (int c = 0; c < 4; ++c) qf[gq][c] = *(const bf16x8*)(qb + c * 32);
    }

    f32x4 oa[2][8];
    f32x4 ls[2];
#pragma unroll
    for (int gq = 0; gq < 2; ++gq) {
      ls[gq] = fzero;
#pragma unroll
      for (int i = 0; i < 8; ++i) oa[gq][i] = fzero;
    }

    const int n_tiles = 2 * qt + 2;           // 64-key tiles, causal bound

    for (int kt = 0; kt < n_tiles; ++kt) {
      const int kv0 = kt * 64;
      __syncthreads();                        // WAR: prior ds_reads drained
#pragma unroll
      for (int cc = 0; cc < 4; ++cc) {
        const int c = w * 4 + cc;
        {  // K tile: 64 rows x 256B; chunk = 4 rows
          const int row = c * 4 + ks_row;
          const int qch = ks_q ^ (row & 15);
          gl_lds16(K + (size_t)(kv0 + row) * kstride + g * HD + qch * 8, (char*)Ks + c * 1024);
        }
        {  // V^T tile: 128 rows x 128B; chunk = 8 rows
          const int row = c * 8 + vs_row;
          gl_lds16(VT + (size_t)(g * HD + row) * SEQ + kv0 + vs_q * 8, (char*)Vs + c * 1024);
        }
      }
      __syncthreads();                        // staged K/V^T visible

      // ---- S = Q K^T ----
      f32x4 s[2][4];
#pragma unroll
      for (int gq = 0; gq < 2; ++gq)
#pragma unroll
        for (int ks = 0; ks < 4; ++ks) s[gq][ks] = fzero;
#pragma unroll
      for (int c = 0; c < 4; ++c)
#pragma unroll
        for (int ks = 0; ks < 4; ++ks) {
          const int row = ks * 16 + l15;
          const int p   = (c * 4 + quad) ^ l15;
          bf16x8 kf = *(const bf16x8*)(Ks + row * 128 + p * 8);
          s[0][ks] = __builtin_amdgcn_mfma_f32_16x16x32_bf16(qf[0][c], kf, s[0][ks], 0, 0, 0);
          s[1][ks] = __builtin_amdgcn_mfma_f32_16x16x32_bf16(qf[1][c], kf, s[1][ks], 0, 0, 0);
        }

      // ---- static softmax: e = exp(s*scale), masked; write P (swizzled) ----
#pragma unroll
      for (int gq = 0; gq < 2; ++gq)
#pragma unroll
        for (int r = 0; r < 4; ++r) {
          const int qrow = qrow0 + gq * 16 + quad * 4 + r;
          const int prow = gq * 16 + quad * 4 + r;
#pragma unroll
          for (int ks = 0; ks < 4; ++ks) {
            const float ex = __expf(s[gq][ks][r] * scale);
            const float e  = (kv0 + ks * 16 + l15 <= qrow) ? ex : 0.f;
            const int qc = ks * 2 + (l15 >> 3);
            const int p  = qc ^ (prow & 7);
            pw[prow * 64 + p * 8 + (l15 & 7)] = f2b(e);
          }
        }
      // no barrier: Ps[w] is per-wave (lgkmcnt orders ds_write->ds_read)

      // ---- O += P V ; ls += P * ones ----
#pragma unroll
      for (int ki = 0; ki < 2; ++ki) {
        bf16x8 pf[2];
#pragma unroll
        for (int gq = 0; gq < 2; ++gq) {
          const int row = gq * 16 + l15;
          const int p   = (ki * 4 + quad) ^ (l15 & 7);
          pf[gq] = *(const bf16x8*)(pw + row * 64 + p * 8);
        }
        ls[0] = __builtin_amdgcn_mfma_f32_16x16x32_bf16(pf[0], onesf, ls[0], 0, 0, 0);
        ls[1] = __builtin_amdgcn_mfma_f32_16x16x32_bf16(pf[1], onesf, ls[1], 0, 0, 0);
#pragma unroll
        for (int nt = 0; nt < 8; ++nt) {
          const int vrow = nt * 16 + l15;
          const int p    = (ki * 4 + quad) ^ (l15 & 7);
          bf16x8 vf = *(const bf16x8*)(Vs + vrow * 64 + p * 8);
          oa[0][nt] = __builtin_amdgcn_mfma_f32_16x16x32_bf16(pf[0], vf, oa[0][nt], 0, 0, 0);
          oa[1][nt] = __builtin_amdgcn_mfma_f32_16x16x32_bf16(pf[1], vf, oa[1][nt], 0, 0, 0);
        }
      }
    }

    // epilogue: divide by rowsum (ls col-replicated), store bf16
#pragma unroll
    for (int gq = 0; gq < 2; ++gq)
#pragma unroll
      for (int r = 0; r < 4; ++r) {
        const float inv = 1.f / ls[gq][r];
        const int qrow = qrow0 + gq * 16 + quad * 4 + r;
        unsigned short* orow = O + (size_t)qrow * DIM + h * HD;
#pragma unroll
        for (int nt = 0; nt < 8; ++nt) orow[nt * 16 + l15] = f2b(oa[gq][nt][r] * inv);
      }
  }
}

// ---------------------------------------------------------------------------
extern "C" void kernel_launch(void* const* d_in, const int* in_sizes, int n_in,
                              void* d_out, int out_size, void* d_ws, size_t ws_size,
                              hipStream_t stream) {
  const float* x  = (const float*)d_in[0];
  const float* wq = (const float*)d_in[1];
  const float* wk = (const float*)d_in[2];
  const float* wv = (const float*)d_in[3];
  const float* wo = (const float*)d_in[4];
  const float* fc = (const float*)d_in[5];
  const float* fs = (const float*)d_in[6];
  float* outp = (float*)d_out;

  const dim3 blk(256);
  const size_t M1 = 1024 * 1024;
  const int nx  = SEQ * DIM;        // 8M
  const int nqw = DIM * DIM;        // 16M
  const int nkw = NKV * HD * DIM;   // 4M
  const int total = SEQ * (NH * 64 + NKV * 64);

  const size_t fused_elems = (8 + 24 + 12 + 2 + 8) * M1;   // 54M elems = 108MB

  if (ws_size >= fused_elems * 2) {
    // ---- fused QKV path ----
    unsigned short* xb   = (unsigned short*)d_ws;
    unsigned short* wbuf = xb   + 8  * M1;   // 24M elems: wq|wk|wv (reused for wo)
    unsigned short* qkv  = wbuf + 24 * M1;   // 12M elems: 2048 x 6144
    unsigned short* vtb  = qkv  + 12 * M1;   // 2M
    unsigned short* aob  = vtb  + 2  * M1;   // 8M

    f32_to_bf16<<<dim3(nx  / 2048), blk, 0, stream>>>(x,  xb, nx);
    f32_to_bf16<<<dim3(nqw / 2048), blk, 0, stream>>>(wq, wbuf, nqw);
    f32_to_bf16<<<dim3(nkw / 2048), blk, 0, stream>>>(wk, wbuf + 16 * M1, nkw);
    f32_to_bf16<<<dim3(nkw / 2048), blk, 0, stream>>>(wv, wbuf + 20 * M1, nkw);

    gemm128<3, false><<<dim3(6144 / 192, SEQ / 128), dim3(512), 0, stream>>>(xb, wbuf, qkv,
                                                                             SEQ, 6144, DIM);

    rope_kernel<<<dim3((total + 255) / 256), blk, 0, stream>>>(qkv, 6144, qkv + 4096, 6144, fc, fs);
    transpose_v<<<dim3(SEQ / 64, 1024 / 64), blk, 0, stream>>>(qkv + 5120, 6144, vtb);
    attn_kernel<<<dim3(256), blk, 0, stream>>>(qkv, 6144, qkv + 4096, 6144, vtb, aob);

    f32_to_bf16<<<dim3(nqw / 2048), blk, 0, stream>>>(wo, wbuf, nqw);
    gemm128<2, true><<<dim3(DIM / 128, SEQ / 128), dim3(512), 0, stream>>>(aob, wbuf, outp,
                                                                           SEQ, DIM, DIM);
  } else {
    // ---- split path (92MB, known-good): q GEMM + fused kv GEMM ----
    unsigned short* xb   = (unsigned short*)d_ws;
    unsigned short* wbuf = xb   + 8  * M1;   // 16M elems
    unsigned short* qb   = wbuf + 16 * M1;   // 8M
    unsigned short* kvb  = qb   + 8  * M1;   // 4M: 2048 x 2048 (k|v)
    unsigned short* vtb  = kvb  + 4  * M1;   // 2M
    unsigned short* aob  = vtb  + 2  * M1;   // 8M

    f32_to_bf16<<<dim3(nx  / 2048), blk, 0, stream>>>(x,  xb, nx);
    f32_to_bf16<<<dim3(nqw / 2048), blk, 0, stream>>>(wq, wbuf, nqw);
    gemm128<2, false><<<dim3(DIM / 128, SEQ / 128), dim3(512), 0, stream>>>(xb, wbuf, qb,
                                                                            SEQ, DIM, DIM);

    f32_to_bf16<<<dim3(nkw / 2048), blk, 0, stream>>>(wk, wbuf, nkw);
    f32_to_bf16<<<dim3(nkw / 2048), blk, 0, stream>>>(wv, wbuf + 4 * M1, nkw);
    gemm_bt<false><<<dim3(2048 / 128, SEQ / 128), blk, 0, stream>>>(xb, wbuf, kvb, SEQ, 2048, DIM);

    rope_kernel<<<dim3((total + 255) / 256), blk, 0, stream>>>(qb, 4096, kvb, 2048, fc, fs);
    transpose_v<<<dim3(SEQ / 64, 1024 / 64), blk, 0, stream>>>(kvb + 1024, 2048, vtb);
    attn_kernel<<<dim3(256), blk, 0, stream>>>(qb, 4096, kvb, 2048, vtb, aob);

    f32_to_bf16<<<dim3(nqw / 2048), blk, 0, stream>>>(wo, wbuf, nqw);
    gemm128<2, true><<<dim3(DIM / 128, SEQ / 128), dim3(512), 0, stream>>>(aob, wbuf, outp,
                                                                           SEQ, DIM, DIM);
  }
}

// Round 8
// 455.134 us; speedup vs baseline: 1.0530x; 1.0273x over previous
//
#include <hip/hip_runtime.h>
#include <cstdint>

// ---------- types ----------
typedef __attribute__((ext_vector_type(8))) __bf16 bf16x8;   // MFMA A/B operand (4 VGPRs)
typedef __attribute__((ext_vector_type(4))) float  f32x4;    // MFMA C/D operand
typedef __attribute__((ext_vector_type(8))) unsigned short ushort8;

#define DIM 4096
#define SEQ 2048
#define NH  32
#define NKV 8
#define HD  128

__device__ __forceinline__ float b2f(unsigned short u) {
  union { unsigned int i; float f; } v; v.i = ((unsigned int)u) << 16; return v.f;
}
__device__ __forceinline__ unsigned short f2b(float f) {
  union { float f; unsigned int i; } v; v.f = f;
  unsigned int r = v.i + 0x7fffu + ((v.i >> 16) & 1u);   // RNE
  return (unsigned short)(r >> 16);
}

// async global->LDS, 16B per lane. LDS dest = wave-uniform base + lane*16.
__device__ __forceinline__ void gl_lds16(const void* g, void* l) {
  __builtin_amdgcn_global_load_lds(
      (const __attribute__((address_space(1))) void*)(uintptr_t)g,
      (__attribute__((address_space(3))) void*)(uintptr_t)l,
      16, 0, 0);
}

// ---------------------------------------------------------------------------
// fp32 -> bf16 conversion (8 elems/thread).
// ---------------------------------------------------------------------------
__global__ __launch_bounds__(256) void f32_to_bf16(const float* __restrict__ src,
                                                   unsigned short* __restrict__ dst, int n) {
  const int i = (blockIdx.x * 256 + threadIdx.x) * 8;
  if (i >= n) return;
  const float4 a = *(const float4*)(src + i);
  const float4 b = *(const float4*)(src + i + 4);
  ushort8 o;
  o[0] = f2b(a.x); o[1] = f2b(a.y); o[2] = f2b(a.z); o[3] = f2b(a.w);
  o[4] = f2b(b.x); o[5] = f2b(b.y); o[6] = f2b(b.z); o[7] = f2b(b.w);
  *(ushort8*)(dst + i) = o;
}

// ---------------------------------------------------------------------------
// GEMM (m97 structure, kept for split-path kv GEMM only).
// ---------------------------------------------------------------------------
template <bool OUT_F32>
__global__ __launch_bounds__(256) void gemm_bt(const unsigned short* __restrict__ A,
                                               const unsigned short* __restrict__ B,
                                               void* __restrict__ Cv,
                                               int M, int N, int K) {
  __shared__ __align__(16) unsigned short As[128 * 32];  // [m][k] rows of 64B
  __shared__ __align__(16) unsigned short Bs[128 * 32];  // [n][k]
  const int n0   = blockIdx.x * 128;
  const int m0   = blockIdx.y * 128;
  const int tid  = threadIdx.x;
  const int w    = tid >> 6;
  const int lane = tid & 63;
  const int quad = lane >> 4;
  const int l15  = lane & 15;
  const int wm   = (w & 1) * 64;
  const int wn   = (w >> 1) * 64;

  const f32x4 fzero = {0.f, 0.f, 0.f, 0.f};
  f32x4 acc[4][4];
#pragma unroll
  for (int i = 0; i < 4; ++i)
#pragma unroll
    for (int j = 0; j < 4; ++j) acc[i][j] = fzero;

  const int srow = lane >> 2;        // chunk = 16 rows of 64B
  const int scol = (lane & 3) * 8;

  for (int k0 = 0; k0 < K; k0 += 32) {
    __syncthreads();
#pragma unroll
    for (int cc = 0; cc < 2; ++cc) {
      const int c   = w * 2 + cc;
      const int row = c * 16 + srow;
      gl_lds16(A + (size_t)(m0 + row) * K + k0 + scol, (char*)As + c * 1024);
      gl_lds16(B + (size_t)(n0 + row) * K + k0 + scol, (char*)Bs + c * 1024);
    }
    __syncthreads();

    bf16x8 af[4], bfr[4];
#pragma unroll
    for (int i = 0; i < 4; ++i) {
      af[i]  = *(const bf16x8*)(As + (wm + i * 16 + l15) * 32 + quad * 8);
      bfr[i] = *(const bf16x8*)(Bs + (wn + i * 16 + l15) * 32 + quad * 8);
    }
#pragma unroll
    for (int i = 0; i < 4; ++i)
#pragma unroll
      for (int j = 0; j < 4; ++j)
        acc[i][j] = __builtin_amdgcn_mfma_f32_16x16x32_bf16(af[i], bfr[j], acc[i][j], 0, 0, 0);
  }

#pragma unroll
  for (int i = 0; i < 4; ++i)
#pragma unroll
    for (int j = 0; j < 4; ++j) {
      const int m = m0 + wm + i * 16 + quad * 4;
      const int n = n0 + wn + j * 16 + l15;
      if (OUT_F32) {
        float* cp = (float*)Cv + (size_t)m * N + n;
#pragma unroll
        for (int r = 0; r < 4; ++r) cp[(size_t)r * N] = acc[i][j][r];
      } else {
        unsigned short* cp = (unsigned short*)Cv + (size_t)m * N + n;
#pragma unroll
        for (int r = 0; r < 4; ++r) cp[(size_t)r * N] = f2b(acc[i][j][r]);
      }
    }
}

// ---------------------------------------------------------------------------
// GEMM 128(M) x NF*32(N), BK=64, 4 waves (2M x 2N), 256 threads.
// Grid 32x16 = 512 blocks = 2 blocks/CU. C = A[M,K]*B[N,K]^T, bf16.
//
// Geometry rationale (round-7 counters): with 2 co-resident blocks the CU
// reaches the LDS-pipe ceiling (measured 3637 cyc/tile-pair ~= LDS model,
// far below the serial sum) -> the binding constraint is LDS BYTES/FLOP =
// (Mw+Nw)/(Mw*Nw) per wave. r7's 64x48 = 0.036 was LDS-bound. This kernel:
// per-wave 64x96 (NF=6, QKV: 0.026 -> MFMA-dominant) or 64x64 (NF=4, wo:
// 0.031 vs r7-wo 0.047). LDS = 2x(128+NF*32)x64x2B = 80/64 KiB -> 2
// blocks/CU; __launch_bounds__(256,2) = 2 waves/EU = 2 blocks/CU.
// K-loop = r5/r7 flat one-barrier structure (verified 3 rounds):
// entry {vmcnt(0) lgkmcnt(0); barrier} -> stage t+1 into buf^1 -> reads+MFMA.
// Swizzle: pre-swizzled global source + XOR ds_read (verified 0 conflicts).
// Accumulation order per element (tiles ascending, ks0 then ks1) unchanged
// -> bit-identical C.
// ---------------------------------------------------------------------------
template <int NF, bool OUT_F32>
__global__ __launch_bounds__(256, 2) void gemm4w(const unsigned short* __restrict__ A,
                                                 const unsigned short* __restrict__ B,
                                                 void* __restrict__ Cv,
                                                 int M, int N, int K) {
  __shared__ __align__(16) unsigned short As[2][128 * 64];
  __shared__ __align__(16) unsigned short Bs[2][NF * 32 * 64];

  const int n0   = blockIdx.x * (NF * 32);
  const int m0   = blockIdx.y * 128;
  const int tid  = threadIdx.x;
  const int w    = tid >> 6;          // 0..3
  const int lane = tid & 63;
  const int quad = lane >> 4;
  const int l15  = lane & 15;
  const int wm   = (w >> 1) * 64;     // 2 waves in M, 64 rows each
  const int wn   = (w & 1) * (NF * 16);  // 2 waves in N, NF*16 cols each

  // staging: chunk = 8 rows x 64 cols (1 KiB); pre-swizzled global source
  // so LDS slot g at row r holds global granule g ^ (r&7)
  const int srow = lane >> 3;
  const int sgr  = (lane & 7) ^ srow;
  const unsigned short* aS = A + (size_t)(m0 + srow) * K + sgr * 8;
  const unsigned short* bS = B + (size_t)(n0 + srow) * K + sgr * 8;

  // ds_read byte offsets: global granule (ks*4+quad) lives at slot (g ^ (l15&7))
  const int gr0 = ((quad)     ^ (l15 & 7)) * 8;
  const int gr1 = ((quad + 4) ^ (l15 & 7)) * 8;

  const f32x4 fzero = {0.f, 0.f, 0.f, 0.f};
  f32x4 acc[4][NF];
#pragma unroll
  for (int i = 0; i < 4; ++i)
#pragma unroll
    for (int j = 0; j < NF; ++j) acc[i][j] = fzero;

  const int NT = K >> 6;

  // prologue: stage tile 0 into buf 0 (4 A-chunks + NF B-chunks per wave)
#pragma unroll
  for (int i = 0; i < 4; ++i) {
    const int c = w * 4 + i;            // A: 16 chunks over 4 waves
    gl_lds16(aS + (size_t)c * 8 * K, (char*)As[0] + c * 1024);
  }
#pragma unroll
  for (int i = 0; i < NF; ++i) {
    const int c = w * NF + i;           // B: NF*4 chunks over 4 waves
    gl_lds16(bS + (size_t)c * 8 * K, (char*)Bs[0] + c * 1024);
  }

  for (int t = 0; t < NT; ++t) {
    const unsigned short* Ab = As[t & 1] + (wm + l15) * 64;
    const unsigned short* Bb = Bs[t & 1] + (wn + l15) * 64;

    // my tile-t gloads landed AND my tile-(t-1) ds_reads drained
    asm volatile("s_waitcnt vmcnt(0) lgkmcnt(0)" ::: "memory");
    __builtin_amdgcn_s_barrier();     // collectively: tile t visible, buf^1 free
    __builtin_amdgcn_sched_barrier(0);

    // stage tile t+1 into the other buffer
    if (t + 1 < NT) {
      const int koff = (t + 1) * 64;
      unsigned short* Ad = As[(t + 1) & 1];
      unsigned short* Bd = Bs[(t + 1) & 1];
#pragma unroll
      for (int i = 0; i < 4; ++i) {
        const int c = w * 4 + i;
        gl_lds16(aS + (size_t)c * 8 * K + koff, (char*)Ad + c * 1024);
      }
#pragma unroll
      for (int i = 0; i < NF; ++i) {
        const int c = w * NF + i;
        gl_lds16(bS + (size_t)c * 8 * K + koff, (char*)Bd + c * 1024);
      }
    }

    // B fragments once, then 2 mf-pair groups; reads grouped per pair so the
    // compiler's counted lgkmcnt overlaps LDS drain with MFMA issue.
    bf16x8 bfr[NF][2];
#pragma unroll
    for (int nf = 0; nf < NF; ++nf) {
      bfr[nf][0] = *(const bf16x8*)(Bb + nf * 1024 + gr0);
      bfr[nf][1] = *(const bf16x8*)(Bb + nf * 1024 + gr1);
    }
#pragma unroll
    for (int mp = 0; mp < 2; ++mp) {
      bf16x8 a0[2], a1[2];
      a0[0] = *(const bf16x8*)(Ab + (mp * 2 + 0) * 1024 + gr0);
      a0[1] = *(const bf16x8*)(Ab + (mp * 2 + 0) * 1024 + gr1);
      a1[0] = *(const bf16x8*)(Ab + (mp * 2 + 1) * 1024 + gr0);
      a1[1] = *(const bf16x8*)(Ab + (mp * 2 + 1) * 1024 + gr1);
      __builtin_amdgcn_s_setprio(1);
#pragma unroll
      for (int ks = 0; ks < 2; ++ks)
#pragma unroll
        for (int nf = 0; nf < NF; ++nf) {
          acc[mp * 2 + 0][nf] = __builtin_amdgcn_mfma_f32_16x16x32_bf16(a0[ks], bfr[nf][ks],
                                                                        acc[mp * 2 + 0][nf], 0, 0, 0);
          acc[mp * 2 + 1][nf] = __builtin_amdgcn_mfma_f32_16x16x32_bf16(a1[ks], bfr[nf][ks],
                                                                        acc[mp * 2 + 1][nf], 0, 0, 0);
        }
      __builtin_amdgcn_s_setprio(0);
    }
  }

#pragma unroll
  for (int mf = 0; mf < 4; ++mf)
#pragma unroll
    for (int nf = 0; nf < NF; ++nf) {
      const int m = m0 + wm + mf * 16 + quad * 4;
      const int n = n0 + wn + nf * 16 + l15;
      if (OUT_F32) {
        float* cp = (float*)Cv + (size_t)m * N + n;
#pragma unroll
        for (int r = 0; r < 4; ++r) cp[(size_t)r * N] = acc[mf][nf][r];
      } else {
        unsigned short* cp = (unsigned short*)Cv + (size_t)m * N + n;
#pragma unroll
        for (int r = 0; r < 4; ++r) cp[(size_t)r * N] = f2b(acc[mf][nf][r]);
      }
    }
}

// ---------------------------------------------------------------------------
// RoPE (interleaved pairs) in-place on bf16 q (S,32,128) and k (S,8,128).
// ---------------------------------------------------------------------------
__global__ void rope_kernel(unsigned short* __restrict__ q, int qstride,
                            unsigned short* __restrict__ k, int kstride,
                            const float* __restrict__ Ct, const float* __restrict__ St) {
  const int idx = blockIdx.x * 256 + threadIdx.x;
  const int total = SEQ * (NH * 64 + NKV * 64);
  if (idx >= total) return;
  const int s = idx / 2560;
  const int r = idx - s * 2560;
  unsigned short* base;
  int i;
  if (r < NH * 64) {
    const int h = r >> 6; i = r & 63;
    base = q + (size_t)s * qstride + h * HD + 2 * i;
  } else {
    const int r2 = r - NH * 64; const int h = r2 >> 6; i = r2 & 63;
    base = k + (size_t)s * kstride + h * HD + 2 * i;
  }
  const float c  = Ct[s * 64 + i];
  const float sn = St[s * 64 + i];
  const float xr = b2f(base[0]);
  const float xi = b2f(base[1]);
  base[0] = f2b(xr * c - xi * sn);
  base[1] = f2b(xr * sn + xi * c);
}

// ---------------------------------------------------------------------------
// V transpose (bf16): v[S][1024] (row stride vstride) -> vt[1024][S]
// ---------------------------------------------------------------------------
__global__ __launch_bounds__(256) void transpose_v(const unsigned short* __restrict__ v,
                                                   int vstride,
                                                   unsigned short* __restrict__ vt) {
  __shared__ unsigned short tile[64][72];
  const int bs = blockIdx.x;
  const int bd = blockIdx.y;
  const int t  = threadIdx.x;
  const int r  = t >> 2;
  const int c0 = (t & 3) * 16;
  const unsigned short* src = v + (size_t)(bs * 64 + r) * vstride + bd * 64 + c0;
#pragma unroll
  for (int i = 0; i < 2; ++i) {
    ushort8 d = *(const ushort8*)(src + i * 8);
#pragma unroll
    for (int e = 0; e < 8; ++e) tile[r][c0 + i * 8 + e] = d[e];
  }
  __syncthreads();
  unsigned short* dst = vt + (size_t)(bd * 64 + r) * SEQ + bs * 64 + c0;
#pragma unroll
  for (int i = 0; i < 2; ++i) {
    ushort8 o;
#pragma unroll
    for (int e = 0; e < 8; ++e) o[e] = tile[c0 + i * 8 + e][r];
    *(ushort8*)(dst + i * 8) = o;
  }
}

// ---------------------------------------------------------------------------
// Flash attention v3 (causal, GQA rep=4), bf16. (unchanged, verified)
// ---------------------------------------------------------------------------
__global__ __launch_bounds__(256) void attn_kernel(const unsigned short* __restrict__ Q, int qstride,
                                                   const unsigned short* __restrict__ K, int kstride,
                                                   const unsigned short* __restrict__ VT,
                                                   unsigned short* __restrict__ O) {
  const int bid  = blockIdx.x;
  const int h    = bid & 31;
  const int pr   = bid >> 5;          // 0..7
  const int g    = h >> 2;            // kv head
  const int tid  = threadIdx.x;
  const int w    = tid >> 6;
  const int lane = tid & 63;
  const int quad = lane >> 4;
  const int l15  = lane & 15;

  __shared__ __align__(16) unsigned short Ks[64 * 128];      // [key][d], swizzled
  __shared__ __align__(16) unsigned short Vs[128 * 64];      // [d][key], swizzled
  __shared__ __align__(16) unsigned short Ps[4][32 * 64];    // per-wave P, swizzled

  const float scale = 0.08838834764831845f;   // 1/sqrt(128)
  const f32x4 fzero = {0.f, 0.f, 0.f, 0.f};

  bf16x8 onesf;
#pragma unroll
  for (int e = 0; e < 8; ++e) onesf[e] = (__bf16)1.0f;

  const int ks_row = (lane >> 4);
  const int ks_q   = (lane & 15);
  const int vs_row = (lane >> 3);
  const int vs_q   = (lane & 7) ^ (lane >> 3);

  unsigned short* pw = Ps[w];

  for (int phase = 0; phase < 2; ++phase) {
    const int qt    = phase ? (15 - pr) : pr;
    const int qrow0 = qt * 128 + w * 32;

    bf16x8 qf[2][4];
#pragma unroll
    for (int gq = 0; gq < 2; ++gq) {
      const unsigned short* qb = Q + (size_t)(qrow0 + gq * 16 + l15) * qstride + h * HD + quad * 8;
#pragma unroll
      for (int c = 0; c < 4; ++c) qf[gq][c] = *(const bf16x8*)(qb + c * 32);
    }

    f32x4 oa[2][8];
    f32x4 ls[2];
#pragma unroll
    for (int gq = 0; gq < 2; ++gq) {
      ls[gq] = fzero;
#pragma unroll
      for (int i = 0; i < 8; ++i) oa[gq][i] = fzero;
    }

    const int n_tiles = 2 * qt + 2;           // 64-key tiles, causal bound

    for (int kt = 0; kt < n_tiles; ++kt) {
      const int kv0 = kt * 64;
      __syncthreads();                        // WAR: prior ds_reads drained
#pragma unroll
      for (int cc = 0; cc < 4; ++cc) {
        const int c = w * 4 + cc;
        {  // K tile: 64 rows x 256B; chunk = 4 rows
          const int row = c * 4 + ks_row;
          const int qch = ks_q ^ (row & 15);
          gl_lds16(K + (size_t)(kv0 + row) * kstride + g * HD + qch * 8, (char*)Ks + c * 1024);
        }
        {  // V^T tile: 128 rows x 128B; chunk = 8 rows
          const int row = c * 8 + vs_row;
          gl_lds16(VT + (size_t)(g * HD + row) * SEQ + kv0 + vs_q * 8, (char*)Vs + c * 1024);
        }
      }
      __syncthreads();                        // staged K/V^T visible

      // ---- S = Q K^T ----
      f32x4 s[2][4];
#pragma unroll
      for (int gq = 0; gq < 2; ++gq)
#pragma unroll
        for (int ks = 0; ks < 4; ++ks) s[gq][ks] = fzero;
#pragma unroll
      for (int c = 0; c < 4; ++c)
#pragma unroll
        for (int ks = 0; ks < 4; ++ks) {
          const int row = ks * 16 + l15;
          const int p   = (c * 4 + quad) ^ l15;
          bf16x8 kf = *(const bf16x8*)(Ks + row * 128 + p * 8);
          s[0][ks] = __builtin_amdgcn_mfma_f32_16x16x32_bf16(qf[0][c], kf, s[0][ks], 0, 0, 0);
          s[1][ks] = __builtin_amdgcn_mfma_f32_16x16x32_bf16(qf[1][c], kf, s[1][ks], 0, 0, 0);
        }

      // ---- static softmax: e = exp(s*scale), masked; write P (swizzled) ----
#pragma unroll
      for (int gq = 0; gq < 2; ++gq)
#pragma unroll
        for (int r = 0; r < 4; ++r) {
          const int qrow = qrow0 + gq * 16 + quad * 4 + r;
          const int prow = gq * 16 + quad * 4 + r;
#pragma unroll
          for (int ks = 0; ks < 4; ++ks) {
            const float ex = __expf(s[gq][ks][r] * scale);
            const float e  = (kv0 + ks * 16 + l15 <= qrow) ? ex : 0.f;
            const int qc = ks * 2 + (l15 >> 3);
            const int p  = qc ^ (prow & 7);
            pw[prow * 64 + p * 8 + (l15 & 7)] = f2b(e);
          }
        }
      // no barrier: Ps[w] is per-wave (lgkmcnt orders ds_write->ds_read)

      // ---- O += P V ; ls += P * ones ----
#pragma unroll
      for (int ki = 0; ki < 2; ++ki) {
        bf16x8 pf[2];
#pragma unroll
        for (int gq = 0; gq < 2; ++gq) {
          const int row = gq * 16 + l15;
          const int p   = (ki * 4 + quad) ^ (l15 & 7);
          pf[gq] = *(const bf16x8*)(pw + row * 64 + p * 8);
        }
        ls[0] = __builtin_amdgcn_mfma_f32_16x16x32_bf16(pf[0], onesf, ls[0], 0, 0, 0);
        ls[1] = __builtin_amdgcn_mfma_f32_16x16x32_bf16(pf[1], onesf, ls[1], 0, 0, 0);
#pragma unroll
        for (int nt = 0; nt < 8; ++nt) {
          const int vrow = nt * 16 + l15;
          const int p    = (ki * 4 + quad) ^ (l15 & 7);
          bf16x8 vf = *(const bf16x8*)(Vs + vrow * 64 + p * 8);
          oa[0][nt] = __builtin_amdgcn_mfma_f32_16x16x32_bf16(pf[0], vf, oa[0][nt], 0, 0, 0);
          oa[1][nt] = __builtin_amdgcn_mfma_f32_16x16x32_bf16(pf[1], vf, oa[1][nt], 0, 0, 0);
        }
      }
    }

    // epilogue: divide by rowsum (ls col-replicated), store bf16
#pragma unroll
    for (int gq = 0; gq < 2; ++gq)
#pragma unroll
      for (int r = 0; r < 4; ++r) {
        const float inv = 1.f / ls[gq][r];
        const int qrow = qrow0 + gq * 16 + quad * 4 + r;
        unsigned short* orow = O + (size_t)qrow * DIM + h * HD;
#pragma unroll
        for (int nt = 0; nt < 8; ++nt) orow[nt * 16 + l15] = f2b(oa[gq][nt][r] * inv);
      }
  }
}

// ---------------------------------------------------------------------------
extern "C" void kernel_launch(void* const* d_in, const int* in_sizes, int n_in,
                              void* d_out, int out_size, void* d_ws, size_t ws_size,
                              hipStream_t stream) {
  const float* x  = (const float*)d_in[0];
  const float* wq = (const float*)d_in[1];
  const float* wk = (const float*)d_in[2];
  const float* wv = (const float*)d_in[3];
  const float* wo = (const float*)d_in[4];
  const float* fc = (const float*)d_in[5];
  const float* fs = (const float*)d_in[6];
  float* outp = (float*)d_out;

  const dim3 blk(256);
  const size_t M1 = 1024 * 1024;
  const int nx  = SEQ * DIM;        // 8M
  const int nqw = DIM * DIM;        // 16M
  const int nkw = NKV * HD * DIM;   // 4M
  const int total = SEQ * (NH * 64 + NKV * 64);

  const size_t fused_elems = (8 + 24 + 12 + 2 + 8) * M1;   // 54M elems = 108MB

  if (ws_size >= fused_elems * 2) {
    // ---- fused QKV path ----
    unsigned short* xb   = (unsigned short*)d_ws;
    unsigned short* wbuf = xb   + 8  * M1;   // 24M elems: wq|wk|wv (reused for wo)
    unsigned short* qkv  = wbuf + 24 * M1;   // 12M elems: 2048 x 6144
    unsigned short* vtb  = qkv  + 12 * M1;   // 2M
    unsigned short* aob  = vtb  + 2  * M1;   // 8M

    f32_to_bf16<<<dim3(nx  / 2048), blk, 0, stream>>>(x,  xb, nx);
    f32_to_bf16<<<dim3(nqw / 2048), blk, 0, stream>>>(wq, wbuf, nqw);
    f32_to_bf16<<<dim3(nkw / 2048), blk, 0, stream>>>(wk, wbuf + 16 * M1, nkw);
    f32_to_bf16<<<dim3(nkw / 2048), blk, 0, stream>>>(wv, wbuf + 20 * M1, nkw);

    gemm4w<6, false><<<dim3(6144 / 192, SEQ / 128), dim3(256), 0, stream>>>(xb, wbuf, qkv,
                                                                            SEQ, 6144, DIM);

    rope_kernel<<<dim3((total + 255) / 256), blk, 0, stream>>>(qkv, 6144, qkv + 4096, 6144, fc, fs);
    transpose_v<<<dim3(SEQ / 64, 1024 / 64), blk, 0, stream>>>(qkv + 5120, 6144, vtb);
    attn_kernel<<<dim3(256), blk, 0, stream>>>(qkv, 6144, qkv + 4096, 6144, vtb, aob);

    f32_to_bf16<<<dim3(nqw / 2048), blk, 0, stream>>>(wo, wbuf, nqw);
    gemm4w<4, true><<<dim3(DIM / 128, SEQ / 128), dim3(256), 0, stream>>>(aob, wbuf, outp,
                                                                          SEQ, DIM, DIM);
  } else {
    // ---- split path (92MB, known-good): q GEMM + fused kv GEMM ----
    unsigned short* xb   = (unsigned short*)d_ws;
    unsigned short* wbuf = xb   + 8  * M1;   // 16M elems
    unsigned short* qb   = wbuf + 16 * M1;   // 8M
    unsigned short* kvb  = qb   + 8  * M1;   // 4M: 2048 x 2048 (k|v)
    unsigned short* vtb  = kvb  + 4  * M1;   // 2M
    unsigned short* aob  = vtb  + 2  * M1;   // 8M

    f32_to_bf16<<<dim3(nx  / 2048), blk, 0, stream>>>(x,  xb, nx);
    f32_to_bf16<<<dim3(nqw / 2048), blk, 0, stream>>>(wq, wbuf, nqw);
    gemm4w<4, false><<<dim3(DIM / 128, SEQ / 128), dim3(256), 0, stream>>>(xb, wbuf, qb,
                                                                           SEQ, DIM, DIM);

    f32_to_bf16<<<dim3(nkw / 2048), blk, 0, stream>>>(wk, wbuf, nkw);
    f32_to_bf16<<<dim3(nkw / 2048), blk, 0, stream>>>(wv, wbuf + 4 * M1, nkw);
    gemm_bt<false><<<dim3(2048 / 128, SEQ / 128), blk, 0, stream>>>(xb, wbuf, kvb, SEQ, 2048, DIM);

    rope_kernel<<<dim3((total + 255) / 256), blk, 0, stream>>>(qb, 4096, kvb, 2048, fc, fs);
    transpose_v<<<dim3(SEQ / 64, 1024 / 64), blk, 0, stream>>>(kvb + 1024, 2048, vtb);
    attn_kernel<<<dim3(256), blk, 0, stream>>>(qb, 4096, kvb, 2048, vtb, aob);

    f32_to_bf16<<<dim3(nqw / 2048), blk, 0, stream>>>(wo, wbuf, nqw);
    gemm4w<4, true><<<dim3(DIM / 128, SEQ / 128), dim3(256), 0, stream>>>(aob, wbuf, outp,
                                                                          SEQ, DIM, DIM);
  }
}